// Round 7
// baseline (751.623 us; speedup 1.0000x reference)
//
#include <hip/hip_runtime.h>
#include <hip/hip_bf16.h>
#include <stdint.h>
#include <stddef.h>

// GlobalLSTMCell — f32 in/out, bf16 MFMA compute, SINGLE fused kernel.
//   ifo = sigmoid(x@W_ifo_x + b_ifo_x + h@W_ifo_h + b_ifo_h); i,f,o = split
//   a   = tanh(x@W_b_x + b_b_x + h@W_b_h + b_b_h)
//   c   = i*a + f*c_prev ; h = o*tanh(c) ; out = [h ; c] f32.
// R10: R9's B-commit was ds_write_b64 at rows 4*lane+c -> 64*lane = 0 mod 32
//     words: zero per-lane bank spread -> 16-way conflict (14.7M counted,
//     ~2900 cyc/K-tile = the whole R9 regression). New B map: thread owns one
//     n-row bn = ((t&1)<<7)|((t>>1)&127) (consecutive lanes alternate row
//     parity -> 16*(row&1) bank bit varies) x k-octets {o1,o1+2}; 16 scalar
//     f32 column loads (2x128B segments/wave, L2-served); 2x ds_write_b128 at
//     slot oct^((bn>>1)&3): banks 16(bn&1)+4(oct^f) = 8 spans x 2 lanes =
//     2-way (free). All reads/A-writes on the same f(row)=(row>>1)&3 (R6's
//     verified-0-conflict swizzle). Publish via counted lgkmcnt(#reads)
//     (in-order DS retirement) instead of R9's full DRAIN.

#define BATCH 4096
#define FEAT  1024
#define HID   1024
#define NCAT  4096
#define KCAT  2048

typedef __attribute__((ext_vector_type(8))) __bf16 bf16x8;
typedef __attribute__((ext_vector_type(4))) float  floatx4;

__device__ __forceinline__ unsigned short f2bf(float f) {
    __hip_bfloat16 b = __float2bfloat16(f);
    return *reinterpret_cast<unsigned short*>(&b);
}

// ---------------- fused pack+GEMM+LSTM (256x256, BK=64, 8-phase) ----------------
#define BM 256
#define BN 256
#define BK 64
#define NIT 16         // 16 iterations x 2 K-tiles = KCAT/BK = 32
#define HALF 8192      // u16 per half-region: 256 rows x 4 slots x 8 u16 (16 KB)

// LDS: A(par,ks) at (par*2+ks)*HALF ; B(par,ks) at 32768 + (par*2+ks)*HALF.
#define A_OFF(PAR, KS) (((PAR) * 2 + (KS)) * HALF)
#define B_OFF(PAR, KS) (32768 + ((PAR) * 2 + (KS)) * HALF)

// ---- A staging: thread t -> row am = t>>1, 16 consecutive k at (t&1)*16 ----
#define ISSUE_A(S, KT, KS) {                                                    \
    const float* s_ = ((KT) < 16) ? (xrow + (KT) * 64 + (KS) * 32)              \
                                  : (hrow + ((KT) - 16) * 64 + (KS) * 32);      \
    S[0] = *(const floatx4*)(s_);      S[1] = *(const floatx4*)(s_ + 4);        \
    S[2] = *(const floatx4*)(s_ + 8);  S[3] = *(const floatx4*)(s_ + 12); }

#define COMMIT_A(S, PAR, KS) {                                                  \
    union { unsigned short u[8]; uint4 v; } w0_, w1_;                           \
    _Pragma("unroll")                                                           \
    for (int e_ = 0; e_ < 4; ++e_) {                                            \
        w0_.u[e_] = f2bf(S[0][e_]); w0_.u[4 + e_] = f2bf(S[1][e_]);             \
        w1_.u[e_] = f2bf(S[2][e_]); w1_.u[4 + e_] = f2bf(S[3][e_]); }           \
    *(uint4*)&lds[A_OFF(PAR, KS) + am * 32 + as0 * 8] = w0_.v;                  \
    *(uint4*)&lds[A_OFF(PAR, KS) + am * 32 + as1 * 8] = w1_.v; }

// ---- B staging: thread owns n-row bn, k-octets {o1, o1+2} (8 k each) ----
// Source: virtual W_cat[k][q]; 16 scalar column loads per half-tile.
#define ISSUE_B(S, KT, KS) {                                                    \
    const int kb_ = (KT) * 64 + (KS) * 32;                                      \
    const float* base_ = (kb_ < 1024)                                           \
        ? (bxcol + (size_t)kb_ * bstride)                                       \
        : (bhcol + (size_t)(kb_ - 1024) * bstride);                             \
    _Pragma("unroll")                                                           \
    for (int i_ = 0; i_ < 8; ++i_) {                                            \
        S[i_]     = base_[(size_t)(bko + i_) * bstride];                        \
        S[i_ + 8] = base_[(size_t)(bko + 16 + i_) * bstride]; } }

#define COMMIT_B(S, PAR, KS) {                                                  \
    union { unsigned short u[8]; uint4 v; } w0_, w1_;                           \
    _Pragma("unroll")                                                           \
    for (int e_ = 0; e_ < 8; ++e_) {                                            \
        w0_.u[e_] = f2bf(S[e_]); w1_.u[e_] = f2bf(S[e_ + 8]); }                 \
    *(uint4*)&lds[B_OFF(PAR, KS) + bn * 32 + bs1 * 8] = w0_.v;                  \
    *(uint4*)&lds[B_OFF(PAR, KS) + bn * 32 + bs2 * 8] = w1_.v; }

#define LOAD_BB(PAR, KS)                                                        \
    _Pragma("unroll")                                                           \
    for (int g_ = 0; g_ < 4; ++g_)                                              \
        bb[g_] = *(const bf16x8*)&lds[B_OFF(PAR, KS) + (wn + g_ * 16 + lm) * 32 + cr];
#define LOAD_AA(PAR, KS, IQ)                                                    \
    _Pragma("unroll")                                                           \
    for (int ii = 0; ii < 4; ++ii)                                              \
        aa[ii] = *(const bf16x8*)&lds[A_OFF(PAR, KS) + (wm + (IQ) * 64 + ii * 16 + lm) * 32 + cr];
#define MFMA16(IQ)                                                              \
    __builtin_amdgcn_s_setprio(1);                                              \
    _Pragma("unroll")                                                           \
    for (int ii = 0; ii < 4; ++ii)                                              \
        _Pragma("unroll")                                                       \
        for (int g_ = 0; g_ < 4; ++g_)                                          \
            acc[(IQ) * 4 + ii][g_] = __builtin_amdgcn_mfma_f32_16x16x32_bf16(   \
                aa[ii], bb[g_], acc[(IQ) * 4 + ii][g_], 0, 0, 0);               \
    __builtin_amdgcn_s_setprio(0);
#define BAR __builtin_amdgcn_s_barrier();
#define WAITK(N) asm volatile("s_waitcnt lgkmcnt(" #N ")" ::: "memory");

__global__ __launch_bounds__(512, 2)
void lstm_one(const float* __restrict__ x, const float* __restrict__ h,
              const float* __restrict__ c_prev,
              const float* __restrict__ Wix, const float* __restrict__ Wih,
              const float* __restrict__ Wbx, const float* __restrict__ Wbh,
              const float* __restrict__ bix, const float* __restrict__ bih,
              const float* __restrict__ bbx, const float* __restrict__ bbh,
              float* __restrict__ out_h, float* __restrict__ out_c) {
    __shared__ unsigned short lds[65536];       // 128 KiB
    const int t    = threadIdx.x;
    const int lane = t & 63;
    const int wid  = t >> 6;                    // 0..7
    const int wm   = (wid >> 2) * 128;          // M-half of block tile
    const int wn   = (wid & 3) * 64;            // N-quarter (one gate-group)
    const int m0   = blockIdx.y * BM;
    const int n0   = blockIdx.x * BN;
    const int lm   = lane & 15;
    const int lk   = lane >> 4;                 // desired k-octet (0..3)
    const int cr   = (lk ^ ((lm >> 1) & 3)) * 8;  // swizzled read slot (u16)

    // ---- A staging map ----
    const int am   = t >> 1;                    // m row 0..255
    const float* xrow = x + (size_t)(m0 + am) * FEAT + (t & 1) * 16;
    const float* hrow = h + (size_t)(m0 + am) * HID  + (t & 1) * 16;
    const int ac0  = (t & 1) * 2;               // first k-octet of this thread
    const int aswz = (am >> 1) & 3;             // = (t>>2)&3
    const int as0  = ac0 ^ aswz;
    const int as1  = (ac0 + 1) ^ aswz;

    // ---- B staging map ----
    // bn: consecutive lanes alternate row parity (bank bit 16*(bn&1) varies).
    const int bn   = ((t & 1) << 7) | ((t >> 1) & 127);   // B LDS row 0..255
    const int bo1  = (t >> 8) & 1;              // first octet (other = +2)
    const int bko  = bo1 * 8;                   // k offset of first octet
    const int bg   = (bn >> 4) & 3;             // gate (n0 multiple of 256)
    const int bj   = (((n0 + bn) >> 6) << 4) | (bn & 15);
    const int bq   = (bg < 3) ? bg * 1024 + bj : bj;
    const int bstride = (bg < 3) ? 3 * HID : HID;
    const float* bxcol = ((bg < 3) ? Wix : Wbx) + bq;
    const float* bhcol = ((bg < 3) ? Wih : Wbh) + bq;
    const int bs1  = bo1 ^ ((bn >> 1) & 3);     // write slots (b128 each)
    const int bs2  = bs1 ^ 2;                   // octet o1+2

    floatx4 acc[8][4];
#pragma unroll
    for (int i = 0; i < 8; ++i)
#pragma unroll
        for (int g = 0; g < 4; ++g) acc[i][g] = (floatx4){0.f, 0.f, 0.f, 0.f};

    floatx4 SO[4];                              // A staging regs (16 f32)
    float   SB[16];                             // B staging regs (16 f32)
    bf16x8 aa[4], bb[4];

    // ---- prologue: K0 both halves + K1-ks0 committed; K1-ks1 issued ----
    ISSUE_A(SO, 0, 0) ISSUE_B(SB, 0, 0)
    COMMIT_A(SO, 0, 0) COMMIT_B(SB, 0, 0)
    ISSUE_A(SO, 0, 1) ISSUE_B(SB, 0, 1)
    COMMIT_A(SO, 0, 1) COMMIT_B(SB, 0, 1)
    ISSUE_A(SO, 1, 0) ISSUE_B(SB, 1, 0)
    COMMIT_A(SO, 1, 0) COMMIT_B(SB, 1, 0)
    ISSUE_A(SO, 1, 1)                           // -> commit at P1
    ISSUE_B(SB, 1, 1)                           // -> commit at P2
    WAITK(0)
    BAR

    for (int it = 0; it < NIT; ++it) {
        const int k2 = 2 * it + 2, k3 = 2 * it + 3;
        const bool more = (it < NIT - 1);

        // P1: commit A(1,1)@k1 | frags(0,0) | issue A@k2 | MFMA(0,0,iq0)
        COMMIT_A(SO, 1, 1)
        LOAD_BB(0, 0) LOAD_AA(0, 0, 0)
        if (more) ISSUE_A(SO, k2, 0)
        WAITK(8) BAR MFMA16(0) BAR
        // P2: commit B(1,1)@k1 | frag | issue B@k2 | MFMA(0,0,iq1)
        COMMIT_B(SB, 1, 1)
        LOAD_AA(0, 0, 1)
        if (more) ISSUE_B(SB, k2, 0)
        WAITK(4) BAR MFMA16(1) BAR
        // P3: commit A(0,0)@k2 | frags(0,1) | issue A(0,1)@k2 | MFMA(0,1,iq0)
        if (more) { COMMIT_A(SO, 0, 0) }
        LOAD_BB(0, 1) LOAD_AA(0, 1, 0)
        if (more) ISSUE_A(SO, k2, 1)
        WAITK(8) BAR MFMA16(0) BAR
        // P4: commit B(0,0)@k2 | frag | issue B(0,1)@k2 | MFMA(0,1,iq1)
        if (more) { COMMIT_B(SB, 0, 0) }
        LOAD_AA(0, 1, 1)
        if (more) ISSUE_B(SB, k2, 1)
        WAITK(4) BAR MFMA16(1) BAR
        // P5: commit A(0,1)@k2 | frags(1,0) | issue A(1,0)@k3 | MFMA(1,0,iq0)
        if (more) { COMMIT_A(SO, 0, 1) }
        LOAD_BB(1, 0) LOAD_AA(1, 0, 0)
        if (more) ISSUE_A(SO, k3, 0)
        WAITK(8) BAR MFMA16(0) BAR
        // P6: commit B(0,1)@k2 | frag | issue B(1,0)@k3 | MFMA(1,0,iq1)
        if (more) { COMMIT_B(SB, 0, 1) }
        LOAD_AA(1, 0, 1)
        if (more) ISSUE_B(SB, k3, 0)
        WAITK(4) BAR MFMA16(1) BAR
        // P7: commit A(1,0)@k3 | frags(1,1) | issue A(1,1)@k3 | MFMA(1,1,iq0)
        if (more) { COMMIT_A(SO, 1, 0) }
        LOAD_BB(1, 1) LOAD_AA(1, 1, 0)
        if (more) ISSUE_A(SO, k3, 1)
        WAITK(8) BAR MFMA16(0) BAR
        // P8: commit B(1,0)@k3 | frag | issue B(1,1)@k3 | MFMA(1,1,iq1)
        if (more) { COMMIT_B(SB, 1, 0) }
        LOAD_AA(1, 1, 1)
        if (more) ISSUE_B(SB, k3, 1)
        WAITK(4) BAR MFMA16(1) BAR
    }

    // ---- LSTM epilogue ----
    // acc[idx][g][r]: m = m0 + wm + idx*16 + (lane>>4)*4 + r,
    //                 gate g at j = ((n0+wn)>>6)*16 + lm.
    const int j  = (((n0 + wn) >> 6) << 4) + lm;
    const float bi = bix[j]           + bih[j];
    const float bf = bix[HID + j]     + bih[HID + j];
    const float bo = bix[2 * HID + j] + bih[2 * HID + j];
    const float ba = bbx[j]           + bbh[j];
#pragma unroll
    for (int i = 0; i < 8; ++i) {
#pragma unroll
        for (int r = 0; r < 4; ++r) {
            int m = m0 + wm + i * 16 + (lk * 4) + r;
            float pi = acc[i][0][r] + bi;
            float pf = acc[i][1][r] + bf;
            float po = acc[i][2][r] + bo;
            float pa = acc[i][3][r] + ba;
            float ig = 1.f / (1.f + __expf(-pi));
            float fg = 1.f / (1.f + __expf(-pf));
            float og = 1.f / (1.f + __expf(-po));
            float av = 2.f / (1.f + __expf(-2.f * pa)) - 1.f;
            float cp = c_prev[(size_t)m * HID + j];
            float cv = ig * av + fg * cp;
            float hv = og * (2.f / (1.f + __expf(-2.f * cv)) - 1.f);
            out_h[(size_t)m * HID + j] = hv;
            out_c[(size_t)m * HID + j] = cv;
        }
    }
}

extern "C" void kernel_launch(void* const* d_in, const int* in_sizes, int n_in,
                              void* d_out, int out_size, void* d_ws, size_t ws_size,
                              hipStream_t stream) {
    const float* x   = (const float*)d_in[0];
    const float* h   = (const float*)d_in[1];
    const float* c   = (const float*)d_in[2];
    const float* Wix = (const float*)d_in[3];
    const float* bix = (const float*)d_in[4];
    const float* Wih = (const float*)d_in[5];
    const float* bih = (const float*)d_in[6];
    const float* Wbx = (const float*)d_in[7];
    const float* bbx = (const float*)d_in[8];
    const float* Wbh = (const float*)d_in[9];
    const float* bbh = (const float*)d_in[10];

    float* out_h = (float*)d_out;
    float* out_c = out_h + (size_t)BATCH * HID;

    lstm_one<<<dim3(NCAT / BN, BATCH / BM), 512, 0, stream>>>(
        x, h, c, Wix, Wih, Wbx, Wbh, bix, bih, bbx, bbh, out_h, out_c);
}

// Round 8
// 277.305 us; speedup vs baseline: 2.7105x; 2.7105x over previous
//
#include <hip/hip_runtime.h>
#include <hip/hip_bf16.h>
#include <stdint.h>
#include <stddef.h>

// GlobalLSTMCell — f32 in/out, bf16 MFMA compute.
//   ifo = sigmoid(x@W_ifo_x + b_ifo_x + h@W_ifo_h + b_ifo_h); i,f,o = split
//   a   = tanh(x@W_b_x + b_b_x + h@W_b_h + b_b_h)
//   c   = i*a + f*c_prev ; h = o*tanh(c) ; out = [h ; c] f32.
// R11: R10's 16-scalar-strided B loads spilled to scratch (709MB writes) ->
//     reverted. Hybrid: pack_wt transposes ONLY the weights (B path needs the
//     k<->n transpose; verified R8 kernel); the GEMM reg-stages A directly
//     from f32 x/h (R9's A path — re-derived conflict-FREE: 8 bank positions
//     x 2 lanes per 16-lane group). Tile shrunk to 128^2/BK64, 4 waves,
//     64 KiB LDS -> TWO blocks resident per CU (grid 1024): two independent
//     barrier groups overlap MFMA vs LDS/stage phases (both pipes were at
//     ~36% in lockstep at 1 block/CU). B staged via global_load_lds from Wt
//     (0-conflict path of R6-R8). B-visibility: compiler's counted vmcnt at
//     each COMMIT_A forces every older B-stage complete >=2 barriers before
//     its first reader (in-order vmcnt retirement; per-phase containment via
//     "memory"-clobber asm at every barrier).

#define BATCH 4096
#define FEAT  1024
#define HID   1024
#define NCAT  4096
#define KCAT  2048

typedef __attribute__((ext_vector_type(8))) __bf16 bf16x8;
typedef __attribute__((ext_vector_type(4))) float  floatx4;

__device__ __forceinline__ unsigned short f2bf(float f) {
    __hip_bfloat16 b = __float2bfloat16(f);
    return *reinterpret_cast<unsigned short*>(&b);
}
__device__ __forceinline__ void gl2lds16(const unsigned short* g, unsigned short* l) {
    __builtin_amdgcn_global_load_lds(
        (const __attribute__((address_space(1))) void*)g,
        (__attribute__((address_space(3))) void*)l, 16, 0, 0);
}

// ---------------- pack_wt: weight transpose only ----------------
// 2048 blocks, 64x64 tiles. Virtual W_cat[k][q]: k<1024 x-weights else
// h-weights; q<3072 -> W_ifo (g=q>>10, j=q&1023) else W_b (g=3, j=q-3072).
// Dest Wt[np][k], np=(j>>4)*64+g*16+(j&15). Chunk-XOR LDS swizzle (R8).
#define TP_PAD 72
__global__ __launch_bounds__(256)
void pack_wt(const float* __restrict__ Wix, const float* __restrict__ Wih,
             const float* __restrict__ Wbx, const float* __restrict__ Wbh,
             unsigned short* __restrict__ Wt) {
    __shared__ unsigned short tile[64 * TP_PAD];
    const int t   = threadIdx.x;
    const int tid = blockIdx.x;
    const int k0  = (tid & 31) * 64;
    const int q0  = (tid >> 5) * 64;
    const float* src; int stride, cb;
    if (q0 < 3072) { src = (k0 < FEAT) ? Wix : Wih; stride = 3072; cb = q0; }
    else           { src = (k0 < FEAT) ? Wbx : Wbh; stride = 1024; cb = q0 - 3072; }
    const int krow = (k0 < FEAT) ? k0 : (k0 - FEAT);
    {   // load 64x64 (k x q) coalesced on q, cvt bf16, swizzled b128 LDS stores
        int kl = t >> 2;
        int cc = t & 3;
        int c0s = ((cc ^ (kl >> 4)) << 4);
        const float* s = src + (size_t)(krow + kl) * stride + cb + cc * 16;
        union { unsigned short s16[16]; uint4 v[2]; } tmp;
#pragma unroll
        for (int u = 0; u < 16; u += 4) {
            float4 v = *(const float4*)(s + u);
            tmp.s16[u + 0] = f2bf(v.x); tmp.s16[u + 1] = f2bf(v.y);
            tmp.s16[u + 2] = f2bf(v.z); tmp.s16[u + 3] = f2bf(v.w);
        }
        *(uint4*)&tile[kl * TP_PAD + c0s]     = tmp.v[0];
        *(uint4*)&tile[kl * TP_PAD + c0s + 8] = tmp.v[1];
    }
    __syncthreads();
    {   // transpose out
        int nl = t >> 2, seg = t & 3;
        int q = q0 + nl;
        int g, j;
        if (q < 3072) { g = q >> 10; j = q & 1023; }
        else          { g = 3;       j = q - 3072; }
        int np = ((j >> 4) << 6) + (g << 4) + (j & 15);
        int ccr = (((nl >> 4) ^ seg) << 4) + (nl & 15);
        union { unsigned short s16[16]; uint4 v[2]; } pk;
#pragma unroll
        for (int u = 0; u < 16; ++u)
            pk.s16[u] = tile[(seg * 16 + u) * TP_PAD + ccr];
        uint4* dst = (uint4*)(Wt + (size_t)np * KCAT + k0 + seg * 16);
        dst[0] = pk.v[0];
        dst[1] = pk.v[1];
    }
}

// ---------------- fused A-pack+GEMM+LSTM (128x128, BK=64, 8-phase) ----------------
#define BM 128
#define BN 128
#define BK 64
#define NIT 16         // 16 iterations x 2 K-tiles = KCAT/BK = 32
#define HALF 4096      // u16 per half-region: 128 rows x 4 slots x 8 u16 (8 KB)

// LDS: A(par,ks) at (par*2+ks)*HALF ; B(par,ks) at 16384 + (par*2+ks)*HALF.
#define A_OFF(PAR, KS) (((PAR) * 2 + (KS)) * HALF)
#define B_OFF(PAR, KS) (16384 + ((PAR) * 2 + (KS)) * HALF)

// ---- A staging (256 thr): thread -> row am = t>>1, 16 k at (t&1)*16 ----
#define ISSUE_A(S, KT, KS) {                                                    \
    const float* s_ = ((KT) < 16) ? (xrow + (KT) * 64 + (KS) * 32)              \
                                  : (hrow + ((KT) - 16) * 64 + (KS) * 32);      \
    S[0] = *(const floatx4*)(s_);      S[1] = *(const floatx4*)(s_ + 4);        \
    S[2] = *(const floatx4*)(s_ + 8);  S[3] = *(const floatx4*)(s_ + 12); }

#define COMMIT_A(S, PAR, KS) {                                                  \
    union { unsigned short u[8]; uint4 v; } w0_, w1_;                           \
    _Pragma("unroll")                                                           \
    for (int e_ = 0; e_ < 4; ++e_) {                                            \
        w0_.u[e_] = f2bf(S[0][e_]); w0_.u[4 + e_] = f2bf(S[1][e_]);             \
        w1_.u[e_] = f2bf(S[2][e_]); w1_.u[4 + e_] = f2bf(S[3][e_]); }           \
    *(uint4*)&lds[A_OFF(PAR, KS) + am * 32 + as0 * 8] = w0_.v;                  \
    *(uint4*)&lds[A_OFF(PAR, KS) + am * 32 + as1 * 8] = w1_.v; }

// ---- B staging from Wt bf16 via gl2lds; source chunk pre-swizzled ----
__device__ __forceinline__ void stage_half(
    const unsigned short* __restrict__ Wt, int n0, int kt, int ks,
    unsigned short* __restrict__ ldsbase, int t) {
#pragma unroll
    for (int u = 0; u < 2; ++u) {
        int hslot = t + u * 256;               // 0..511
        int row   = hslot >> 2;                // 0..127
        int c     = (hslot & 3) ^ ((row >> 1) & 3);
        gl2lds16(Wt + (size_t)(n0 + row) * KCAT + kt * BK + ks * 32 + c * 8,
                 ldsbase + hslot * 8);
    }
}

#define LOAD_BB(PAR, KS)                                                        \
    _Pragma("unroll")                                                           \
    for (int g_ = 0; g_ < 4; ++g_)                                              \
        bb[g_] = *(const bf16x8*)&lds[B_OFF(PAR, KS) + (wn + g_ * 16 + lm) * 32 + cr];
#define LOAD_AA2(PAR, KS, IH)                                                   \
    _Pragma("unroll")                                                           \
    for (int ii = 0; ii < 2; ++ii)                                              \
        aa[ii] = *(const bf16x8*)&lds[A_OFF(PAR, KS) + (wm + (IH) * 32 + ii * 16 + lm) * 32 + cr];
#define MFMA8(IH)                                                               \
    __builtin_amdgcn_s_setprio(1);                                              \
    _Pragma("unroll")                                                           \
    for (int ii = 0; ii < 2; ++ii)                                              \
        _Pragma("unroll")                                                       \
        for (int g_ = 0; g_ < 4; ++g_)                                          \
            acc[(IH) * 2 + ii][g_] = __builtin_amdgcn_mfma_f32_16x16x32_bf16(   \
                aa[ii], bb[g_], acc[(IH) * 2 + ii][g_], 0, 0, 0);               \
    __builtin_amdgcn_s_setprio(0);
#define BAR __builtin_amdgcn_s_barrier();
#define WAITK(N) asm volatile("s_waitcnt lgkmcnt(" #N ")" ::: "memory");

__global__ __launch_bounds__(256, 2)
void lstm_fused(const float* __restrict__ x, const float* __restrict__ h,
                const unsigned short* __restrict__ Wt,
                const float* __restrict__ c_prev,
                const float* __restrict__ bix, const float* __restrict__ bih,
                const float* __restrict__ bbx, const float* __restrict__ bbh,
                float* __restrict__ out_h, float* __restrict__ out_c) {
    __shared__ unsigned short lds[32768];       // 64 KiB -> 2 blocks/CU
    const int t    = threadIdx.x;
    const int lane = t & 63;
    const int wid  = t >> 6;                    // 0..3
    const int wm   = (wid >> 1) * 64;           // M-half of block tile
    const int wn   = (wid & 1) * 64;            // N-half (one gate-group)
    const int m0   = blockIdx.y * BM;
    const int n0   = blockIdx.x * BN;
    const int lm   = lane & 15;
    const int lk   = lane >> 4;                 // desired k-chunk (0..3)
    const int cr   = (lk ^ ((lm >> 1) & 3)) * 8;  // swizzled read slot (u16)

    // ---- A staging map (conflict-free: 8 positions x 2 lanes / 16-lane grp) ----
    const int am   = t >> 1;                    // m row 0..127
    const float* xrow = x + (size_t)(m0 + am) * FEAT + (t & 1) * 16;
    const float* hrow = h + (size_t)(m0 + am) * HID  + (t & 1) * 16;
    const int ac0  = (t & 1) * 2;
    const int aswz = (am >> 1) & 3;
    const int as0  = ac0 ^ aswz;
    const int as1  = (ac0 + 1) ^ aswz;

    floatx4 acc[4][4];
#pragma unroll
    for (int i = 0; i < 4; ++i)
#pragma unroll
        for (int g = 0; g < 4; ++g) acc[i][g] = (floatx4){0.f, 0.f, 0.f, 0.f};

    floatx4 SO[4];
    bf16x8 aa[2], bb[4];

    // ---- prologue: A(0,0),(0,1),(1,0) committed; B all 4 staged; A(1,1) issued ----
    ISSUE_A(SO, 0, 0) COMMIT_A(SO, 0, 0)
    ISSUE_A(SO, 0, 1) COMMIT_A(SO, 0, 1)
    ISSUE_A(SO, 1, 0) COMMIT_A(SO, 1, 0)
    stage_half(Wt, n0, 0, 0, lds + B_OFF(0, 0), t);
    stage_half(Wt, n0, 0, 1, lds + B_OFF(0, 1), t);
    stage_half(Wt, n0, 1, 0, lds + B_OFF(1, 0), t);
    stage_half(Wt, n0, 1, 1, lds + B_OFF(1, 1), t);
    ISSUE_A(SO, 1, 1)                           // commit at P1
    asm volatile("s_waitcnt vmcnt(4)" ::: "memory");  // all B staged; A(1,1) in flight
    WAITK(0)
    BAR

    for (int it = 0; it < NIT; ++it) {
        const int k2 = 2 * it + 2, k3 = 2 * it + 3;
        const bool more = (it < NIT - 1);

        // P1: commit A(1,1)@k-odd | frags(0,0,ih0) | issue A(0,0)@k2
        COMMIT_A(SO, 1, 1)
        LOAD_BB(0, 0) LOAD_AA2(0, 0, 0)
        if (more) ISSUE_A(SO, k2, 0)
        WAITK(6) BAR MFMA8(0) BAR
        // P2: stage B(0,0)@k2 | frags(0,0,ih1)
        if (more) stage_half(Wt, n0, k2, 0, lds + B_OFF(0, 0), t);
        LOAD_AA2(0, 0, 1)
        BAR MFMA8(1) BAR
        // P3: commit A(0,0)@k2 | frags(0,1,ih0) | issue A(0,1)@k2
        if (more) { COMMIT_A(SO, 0, 0) }
        LOAD_BB(0, 1) LOAD_AA2(0, 1, 0)
        if (more) ISSUE_A(SO, k2, 1)
        WAITK(6) BAR MFMA8(0) BAR
        // P4: stage B(0,1)@k2 | frags(0,1,ih1)
        if (more) stage_half(Wt, n0, k2, 1, lds + B_OFF(0, 1), t);
        LOAD_AA2(0, 1, 1)
        BAR MFMA8(1) BAR
        // P5: commit A(0,1)@k2 | frags(1,0,ih0) | issue A(1,0)@k3
        if (more) { COMMIT_A(SO, 0, 1) }
        LOAD_BB(1, 0) LOAD_AA2(1, 0, 0)
        if (more) ISSUE_A(SO, k3, 0)
        WAITK(6) BAR MFMA8(0) BAR
        // P6: stage B(1,0)@k3 | frags(1,0,ih1)
        if (more) stage_half(Wt, n0, k3, 0, lds + B_OFF(1, 0), t);
        LOAD_AA2(1, 0, 1)
        BAR MFMA8(1) BAR
        // P7: commit A(1,0)@k3 | frags(1,1,ih0) | issue A(1,1)@k3
        if (more) { COMMIT_A(SO, 1, 0) }
        LOAD_BB(1, 1) LOAD_AA2(1, 1, 0)
        if (more) ISSUE_A(SO, k3, 1)
        WAITK(6) BAR MFMA8(0) BAR
        // P8: stage B(1,1)@k3 | frags(1,1,ih1)
        if (more) stage_half(Wt, n0, k3, 1, lds + B_OFF(1, 1), t);
        LOAD_AA2(1, 1, 1)
        BAR MFMA8(1) BAR
    }

    // ---- LSTM epilogue ----
    // acc[i][g][r]: m = m0 + wm + i*16 + (lane>>4)*4 + r,
    //               gate g at j = ((n0+wn)>>6)*16 + lm.
    const int j  = (((n0 + wn) >> 6) << 4) + lm;
    const float bi = bix[j]           + bih[j];
    const float bf = bix[HID + j]     + bih[HID + j];
    const float bo = bix[2 * HID + j] + bih[2 * HID + j];
    const float ba = bbx[j]           + bbh[j];
#pragma unroll
    for (int i = 0; i < 4; ++i) {
#pragma unroll
        for (int r = 0; r < 4; ++r) {
            int m = m0 + wm + i * 16 + (lk * 4) + r;
            float pi = acc[i][0][r] + bi;
            float pf = acc[i][1][r] + bf;
            float po = acc[i][2][r] + bo;
            float pa = acc[i][3][r] + ba;
            float ig = 1.f / (1.f + __expf(-pi));
            float fg = 1.f / (1.f + __expf(-pf));
            float og = 1.f / (1.f + __expf(-po));
            float av = 2.f / (1.f + __expf(-2.f * pa)) - 1.f;
            float cp = c_prev[(size_t)m * HID + j];
            float cv = ig * av + fg * cp;
            float hv = og * (2.f / (1.f + __expf(-2.f * cv)) - 1.f);
            out_h[(size_t)m * HID + j] = hv;
            out_c[(size_t)m * HID + j] = cv;
        }
    }
}

// ---------------- naive fallback (ws too small) ----------------
__global__ void naive_lstm(const float* __restrict__ x, const float* __restrict__ h,
                           const float* __restrict__ cvp,
                           const float* __restrict__ Wix, const float* __restrict__ bix,
                           const float* __restrict__ Wih, const float* __restrict__ bih,
                           const float* __restrict__ Wbx, const float* __restrict__ bbx,
                           const float* __restrict__ Wbh, const float* __restrict__ bbh,
                           float* __restrict__ out_h, float* __restrict__ out_c) {
    const int j = blockIdx.x * 256 + threadIdx.x;
    const int m = blockIdx.y;
    float ai = 0.f, af = 0.f, ao = 0.f, aa = 0.f;
    for (int k = 0; k < FEAT; ++k) {
        float xk = x[(size_t)m * FEAT + k];
        ai += xk * Wix[(size_t)k * 3072 + j];
        af += xk * Wix[(size_t)k * 3072 + HID + j];
        ao += xk * Wix[(size_t)k * 3072 + 2 * HID + j];
        aa += xk * Wbx[(size_t)k * HID + j];
    }
    for (int k = 0; k < HID; ++k) {
        float hk = h[(size_t)m * HID + k];
        ai += hk * Wih[(size_t)k * 3072 + j];
        af += hk * Wih[(size_t)k * 3072 + HID + j];
        ao += hk * Wih[(size_t)k * 3072 + 2 * HID + j];
        aa += hk * Wbh[(size_t)k * HID + j];
    }
    ai += bix[j] + bih[j];
    af += bix[HID + j] + bih[HID + j];
    ao += bix[2 * HID + j] + bih[2 * HID + j];
    aa += bbx[j] + bbh[j];
    float ig = 1.f / (1.f + __expf(-ai));
    float fg = 1.f / (1.f + __expf(-af));
    float og = 1.f / (1.f + __expf(-ao));
    float av = 2.f / (1.f + __expf(-2.f * aa)) - 1.f;
    float cp = cvp[(size_t)m * HID + j];
    float cc = ig * av + fg * cp;
    float hh = og * (2.f / (1.f + __expf(-2.f * cc)) - 1.f);
    out_h[(size_t)m * HID + j] = hh;
    out_c[(size_t)m * HID + j] = cc;
}

extern "C" void kernel_launch(void* const* d_in, const int* in_sizes, int n_in,
                              void* d_out, int out_size, void* d_ws, size_t ws_size,
                              hipStream_t stream) {
    const float* x   = (const float*)d_in[0];
    const float* h   = (const float*)d_in[1];
    const float* c   = (const float*)d_in[2];
    const float* Wix = (const float*)d_in[3];
    const float* bix = (const float*)d_in[4];
    const float* Wih = (const float*)d_in[5];
    const float* bih = (const float*)d_in[6];
    const float* Wbx = (const float*)d_in[7];
    const float* bbx = (const float*)d_in[8];
    const float* Wbh = (const float*)d_in[9];
    const float* bbh = (const float*)d_in[10];

    float* out_h = (float*)d_out;
    float* out_c = out_h + (size_t)BATCH * HID;

    const size_t WT_BYTES = (size_t)NCAT * KCAT * 2;    // 16 MiB
    if (ws_size >= WT_BYTES) {
        unsigned short* Wt = (unsigned short*)d_ws;
        pack_wt<<<2048, 256, 0, stream>>>(Wix, Wih, Wbx, Wbh, Wt);
        lstm_fused<<<dim3(NCAT / BN, BATCH / BM), 256, 0, stream>>>(
            x, h, Wt, c, bix, bih, bbx, bbh, out_h, out_c);
    } else {
        naive_lstm<<<dim3(HID / 256, BATCH), 256, 0, stream>>>(
            x, h, c, Wix, bix, Wih, bih, Wbx, bbx, Wbh, bbh, out_h, out_c);
    }
}